// Round 13
// baseline (290.336 us; speedup 1.0000x reference)
//
#include <hip/hip_runtime.h>

#define N_NODESC 100000
#define N_EDGESC 600000
#define E_TOTC   700000
#define NUM_GRAPHSC 512
#define NEG_SLOPE 0.2f
#define NEG_INF_ENC 0x007FFFFFu
#define SCAN_NB 128

typedef unsigned short ushort_t;
typedef __attribute__((ext_vector_type(8))) short bf16x8;   // 8 bf16 = 4 VGPR
typedef __attribute__((ext_vector_type(4))) float f32x4;    // MFMA accumulator

// monotone float<->uint mapping so unsigned atomicMax == float max
__device__ __forceinline__ unsigned enc_f32(float f) {
    unsigned u = __float_as_uint(f);
    return (u & 0x80000000u) ? ~u : (u | 0x80000000u);
}
__device__ __forceinline__ float dec_f32(unsigned u) {
    u = (u & 0x80000000u) ? (u ^ 0x80000000u) : ~u;
    return __uint_as_float(u);
}
// exact fp32->bf16 RNE (finite values) and bf16->fp32
__device__ __forceinline__ ushort_t f32_to_bf16(float f) {
    unsigned u = __float_as_uint(f);
    return (ushort_t)((u + 0x7FFFu + ((u >> 16) & 1u)) >> 16);
}
__device__ __forceinline__ float bf16_to_f32(ushort_t h) {
    return __uint_as_float(((unsigned)h) << 16);
}
__device__ __forceinline__ unsigned pack_bf16x2(float a, float b) {
    return (unsigned)f32_to_bf16(a) | ((unsigned)f32_to_bf16(b) << 16);
}

// register-free async global->LDS, width 16B (vmcnt-counted, no VGPR dest)
__device__ __forceinline__ void glds16(const void* g, void* l) {
    __builtin_amdgcn_global_load_lds(
        (const __attribute__((address_space(1))) void*)g,
        (__attribute__((address_space(3))) void*)l, 16, 0, 0);
}

// fused init: msum=0, mmax=-inf, cnt=0, deg=0, W1/W2 -> bf16 wPre, and
// v17: X -> bf16 (grid-strided; same RNE gemm1 applied in-kernel before, so
// downstream numerics are BITWISE identical). Grid covers N*128/8 threads.
__global__ __launch_bounds__(256) void init_all(float* __restrict__ msum,
                                                unsigned* __restrict__ mmax,
                                                float* __restrict__ cnt,
                                                int* __restrict__ deg,
                                                const float* __restrict__ W1,
                                                const float* __restrict__ W2,
                                                ushort_t* __restrict__ wPre1,
                                                ushort_t* __restrict__ wPre2,
                                                const float* __restrict__ X,
                                                ushort_t* __restrict__ xb16) {
    int i = blockIdx.x * 256 + threadIdx.x;
    if (i < NUM_GRAPHSC * 64) { msum[i] = 0.f; mmax[i] = NEG_INF_ENC; }
    if (i < NUM_GRAPHSC) cnt[i] = 0.f;
    if (i < N_NODESC) deg[i] = 0;
    if (i < 128 * 128) {
        int n = i >> 7, k = i & 127;
        wPre1[n * 128 + k] = f32_to_bf16(W1[k * 128 + n]);
    } else if (i < 128 * 128 + 64 * 128) {
        int j = i - 128 * 128;
        int n = j >> 7, k = j & 127;
        wPre2[n * 128 + k] = f32_to_bf16(W2[k * 64 + n]);
    }
    if (i < N_NODESC * 128 / 8) {
        const float4* xp = (const float4*)(X + (size_t)i * 8);
        float4 a = xp[0], b = xp[1];
        uint4 o;
        o.x = pack_bf16x2(a.x, a.y);
        o.y = pack_bf16x2(a.z, a.w);
        o.z = pack_bf16x2(b.x, b.y);
        o.w = pack_bf16x2(b.z, b.w);
        *(uint4*)(xb16 + (size_t)i * 8) = o;
    }
}

// ---------------- CSR build (hist fused into gemm1 in v17) ----------------
__global__ __launch_bounds__(256) void scan_partial(const int* __restrict__ deg,
                                                    int* __restrict__ bsum, int n) {
    __shared__ int red[256];
    int chunk = (n + SCAN_NB - 1) / SCAN_NB;
    int lo = blockIdx.x * chunk, hi = min(lo + chunk, n);
    int s = 0;
    for (int i = lo + threadIdx.x; i < hi; i += 256) s += deg[i];
    red[threadIdx.x] = s;
    __syncthreads();
    for (int d = 128; d; d >>= 1) {
        if (threadIdx.x < d) red[threadIdx.x] += red[threadIdx.x + d];
        __syncthreads();
    }
    if (threadIdx.x == 0) bsum[blockIdx.x] = red[0];
}

__global__ __launch_bounds__(256) void scan_final(const int* __restrict__ deg,
                                                  const int* __restrict__ bsum,
                                                  int* __restrict__ off, int n) {
    __shared__ int bs[SCAN_NB];
    __shared__ int tile[256];
    __shared__ int carry;
    int t = threadIdx.x;
    if (t < SCAN_NB) bs[t] = bsum[t];
    __syncthreads();
    for (int d = 1; d < SCAN_NB; d <<= 1) {
        int v = (t >= d && t < SCAN_NB) ? bs[t - d] : 0;
        __syncthreads();
        if (t < SCAN_NB) bs[t] += v;
        __syncthreads();
    }
    if (t == 0) carry = blockIdx.x ? bs[blockIdx.x - 1] : 0;
    __syncthreads();
    int chunk = (n + SCAN_NB - 1) / SCAN_NB;
    int lo = blockIdx.x * chunk, hi = min(lo + chunk, n);
    for (int base = lo; base < hi; base += 256) {
        int i = base + t;
        int v = (i < hi) ? deg[i] : 0;
        tile[t] = v;
        __syncthreads();
        for (int d = 1; d < 256; d <<= 1) {
            int u = (t >= d) ? tile[t - d] : 0;
            __syncthreads();
            tile[t] += u;
            __syncthreads();
        }
        if (i < hi) off[i] = carry + tile[t] - v;
        __syncthreads();
        if (t == 0) carry += tile[255];
        __syncthreads();
    }
}

__global__ __launch_bounds__(256) void scatter_csr(const int* __restrict__ ei,
                                                   int* __restrict__ off,
                                                   int* __restrict__ csr) {
    int e = blockIdx.x * blockDim.x + threadIdx.x;
    if (e >= E_TOTC) return;
    int s, d;
    if (e < N_EDGESC) { s = ei[e]; d = ei[N_EDGESC + e]; } else { s = d = e - N_EDGESC; }
    int slot = atomicAdd(&off[d], 1);
    csr[slot] = s;
}

// ---------------- MFMA GEMM, layer 1 (v17: bf16 input, gemm2-proven path) ---
// R25: gemm1 streamed X as FP32 (51.2MB, 8 glds/tile) and packed to bf16
// in-kernel. v17 pre-converts X once (streaming, in init_all) and gemm1
// becomes the gemm2-proven bf16 structure: 4 glds x 1KB (4 rows each), direct
// bf16x8 LDS reads, same swizzle relation -- half the staged bytes/requests.
// hist_dst is FUSED here (independent work, issued between glds and the
// vmcnt wait -> hides under staging latency; scan launches after this kernel
// so deg is complete). Y-write + in-wave alpha epilogue verbatim from v11.
// Fragment maps (m89/m91): A[m=lane&15][k=quad*8+j], B[n=lane&15][k=quad*8+j],
// D[row=quad*4+r][col=lane&15]. Y u32 col c = pack(head0 ch c, head1 ch c).
__global__ __launch_bounds__(64) void gemm1_mfma(const ushort_t* __restrict__ Xb,
                                                 const ushort_t* __restrict__ Wp,
                                                 const float* __restrict__ a_s,
                                                 const float* __restrict__ a_d,
                                                 float* __restrict__ as_out,
                                                 float* __restrict__ ad_out,
                                                 ushort_t* __restrict__ Y16,
                                                 const int* __restrict__ ei,
                                                 int* __restrict__ deg, int N) {
    __shared__ ushort_t sx[2048];    // 4KB: 16 rows x 256B, source-swizzled
    int lane = threadIdx.x;
    int quad = lane >> 4, l16 = lane & 15;
    size_t node0 = (size_t)blockIdx.x * 16;

    // stage the tile: 4 chunks x 1KB (4 rows each) -- gemm2-proven geometry
    {
        int rq = lane >> 4;               // row within 4-row chunk
        int cb = (lane & 15) * 16;        // col byte 0..240
#pragma unroll
        for (int c = 0; c < 4; ++c) {
            int rl = 4 * c + rq;
            size_t grow = node0 + rl;
            if (grow >= (size_t)N) grow = N - 1;   // pad rows: consistent garbage
            int goff = cb ^ ((rl & 15) << 4);      // inverse swizzle on SOURCE
            glds16((const char*)(Xb + grow * 128) + goff,
                   (char*)sx + c * 1024);
        }
    }
    // fused hist: independent of staging; overlaps the glds latency.
    for (int e = blockIdx.x * 64 + lane; e < E_TOTC; e += 6250 * 64) {
        int d = (e < N_EDGESC) ? ei[N_EDGESC + e] : e - N_EDGESC;
        atomicAdd(&deg[d], 1);
    }
    asm volatile("s_waitcnt vmcnt(0)" ::: "memory");
    __builtin_amdgcn_sched_barrier(0);

    const char* swx = (const char*)sx + l16 * 256;
    int skey = (l16 & 15) << 4;

    f32x4 acc[8];
#pragma unroll
    for (int ct = 0; ct < 8; ++ct) acc[ct] = (f32x4){0.f, 0.f, 0.f, 0.f};

#pragma unroll
    for (int kc = 0; kc < 4; ++kc) {
        int b = kc * 64 + quad * 16;      // byte of k = kc*32 + quad*8 (bf16)
        bf16x8 a = *(const bf16x8*)(swx + (b ^ skey));
#pragma unroll
        for (int ct = 0; ct < 8; ++ct) {
            bf16x8 bb = *(const bf16x8*)(Wp + (size_t)(ct * 16 + l16) * 128 + kc * 32 + quad * 8);
            acc[ct] = __builtin_amdgcn_mfma_f32_16x16x32_bf16(a, bb, acc[ct], 0, 0, 0);
        }
    }

    // Y write (clean full rows) + in-wave alpha (plain stores) [v11 verbatim]
    unsigned* Yu = (unsigned*)Y16;
    float asv0[4], asv1[4], adv0[4], adv1[4];
#pragma unroll
    for (int ct = 0; ct < 4; ++ct) {
        int c = ct * 16 + l16;
        asv0[ct] = a_s[c]; asv1[ct] = a_s[64 + c];
        adv0[ct] = a_d[c]; adv1[ct] = a_d[64 + c];
    }
#pragma unroll
    for (int r = 0; r < 4; ++r) {
        size_t row = node0 + quad * 4 + r;
        bool ok = row < (size_t)N;
        if (ok) {
#pragma unroll
            for (int ct = 0; ct < 4; ++ct)
                Yu[row * 64 + ct * 16 + l16] = pack_bf16x2(acc[ct][r], acc[ct + 4][r]);
        }
        float ps0 = 0.f, pd0 = 0.f, ps1 = 0.f, pd1 = 0.f;
#pragma unroll
        for (int ct = 0; ct < 4; ++ct) {
            ps0 += acc[ct][r] * asv0[ct];     pd0 += acc[ct][r] * adv0[ct];
            ps1 += acc[ct + 4][r] * asv1[ct]; pd1 += acc[ct + 4][r] * adv1[ct];
        }
#pragma unroll
        for (int sh = 1; sh < 16; sh <<= 1) {
            ps0 += __shfl_xor(ps0, sh); pd0 += __shfl_xor(pd0, sh);
            ps1 += __shfl_xor(ps1, sh); pd1 += __shfl_xor(pd1, sh);
        }
        if (l16 == 0 && ok) {
            *(float2*)(as_out + row * 2) = make_float2(ps0, ps1);
            *(float2*)(ad_out + row * 2) = make_float2(pd0, pd1);
        }
    }
}

// ---------------- fused gather aggregation (v16 body, unchanged) ------------
template <int H, bool RELU, bool FUSE2, bool FPOOL>
__global__ __launch_bounds__(256) void gat_gather(const int* __restrict__ off_end,
                                                  const int* __restrict__ deg,
                                                  const int* __restrict__ csr,
                                                  const float* __restrict__ as,
                                                  const float* __restrict__ ad,
                                                  const ushort_t* __restrict__ H16,
                                                  const float* __restrict__ b,
                                                  void* __restrict__ outp,
                                                  const ushort_t* __restrict__ Wp2,
                                                  const float* __restrict__ as2v,
                                                  const float* __restrict__ ad2v,
                                                  float* __restrict__ as2o,
                                                  float* __restrict__ ad2o,
                                                  ushort_t* __restrict__ h2out,
                                                  const int* __restrict__ batchp,
                                                  float* __restrict__ msum,
                                                  unsigned* __restrict__ mmax,
                                                  float* __restrict__ cntb,
                                                  int N) {
    __shared__ char h1tile[16 * 256];      // FUSE2: swizzled h1 rows / FPOOL: [16][64] f32
    __shared__ float aspart[16][4];
    __shared__ float adpart[16][4];
    __shared__ int batch_l[16];
    int lane = threadIdx.x & 63;
    int wave = threadIdx.x >> 6;
    int l = lane & 15;          // lane within group
    int gbase = lane & 48;      // group base lane in wave
    int n = blockIdx.x * 16 + wave * 4 + (lane >> 4);
    if (n >= N) return;         // never taken (N%16==0, exact grid)
    int dg = deg[n];
    int o = off_end[n] - dg;
    float adv[H];
#pragma unroll
    for (int h = 0; h < H; ++h) adv[h] = ad[n * H + h];

    float acc[H][4], den[H];
#pragma unroll
    for (int h = 0; h < H; ++h) {
        den[h] = 0.f;
#pragma unroll
        for (int q = 0; q < 4; ++q) acc[h][q] = 0.f;
    }

    const unsigned* Hu = (const unsigned*)H16;  // H==2: row = 64 u32 interleaved

    for (int base = 0; base < dg; base += 16) {
        int i = base + l;
        bool valid = i < dg;
        int s = valid ? csr[o + i] : 0;
        float v[H];
        if (H == 2) {
            float2 p = valid ? ((const float2*)as)[s] : make_float2(0.f, 0.f);
            v[0] = p.x + adv[0];
            v[H - 1] = p.y + adv[H - 1];
        } else {
            v[0] = valid ? as[s] + adv[0] : 0.f;
        }
#pragma unroll
        for (int h = 0; h < H; ++h) {
            float e = v[h] >= 0.f ? v[h] : NEG_SLOPE * v[h];
            v[h] = valid ? __expf(e) : 0.f;  // weight; 0 for invalid lanes
            den[h] += v[h];
        }
        int wpk = (H == 2) ? (int)pack_bf16x2(v[0], v[H - 1])
                           : (int)__float_as_uint(v[0]);
        int cnt = min(dg - base, 16);
        int cnt4 = (cnt + 3) & ~3;  // pad: lanes >= cnt have weight 0, s = 0
        for (int j = 0; j < cnt4; j += 4) {
#pragma unroll
            for (int u = 0; u < 4; ++u) {
                int src = gbase + j + u;     // per-lane index: serves all groups
                int sj = __shfl(s, src);
                int wp = __shfl(wpk, src);
                if (H == 2) {
                    float w0 = __uint_as_float(((unsigned)wp) << 16);
                    float w1 = __uint_as_float(((unsigned)wp) & 0xffff0000u);
                    uint4 hu = *(const uint4*)(Hu + (size_t)sj * 64 + l * 4);
                    acc[0][0] += w0 * __uint_as_float(hu.x << 16);
                    acc[H - 1][0] += w1 * __uint_as_float(hu.x & 0xffff0000u);
                    acc[0][1] += w0 * __uint_as_float(hu.y << 16);
                    acc[H - 1][1] += w1 * __uint_as_float(hu.y & 0xffff0000u);
                    acc[0][2] += w0 * __uint_as_float(hu.z << 16);
                    acc[H - 1][2] += w1 * __uint_as_float(hu.z & 0xffff0000u);
                    acc[0][3] += w0 * __uint_as_float(hu.w << 16);
                    acc[H - 1][3] += w1 * __uint_as_float(hu.w & 0xffff0000u);
                } else {
                    float w0 = __uint_as_float((unsigned)wp);
                    uint2 hu = *(const uint2*)((const unsigned*)(H16 + (size_t)sj * 64) + l * 2);
                    acc[0][0] += w0 * __uint_as_float(hu.x << 16);
                    acc[0][1] += w0 * __uint_as_float(hu.x & 0xffff0000u);
                    acc[0][2] += w0 * __uint_as_float(hu.y << 16);
                    acc[0][3] += w0 * __uint_as_float(hu.y & 0xffff0000u);
                }
            }
        }
    }
#pragma unroll
    for (int h = 0; h < H; ++h) {
#pragma unroll
        for (int sh = 8; sh; sh >>= 1) den[h] += __shfl_xor(den[h], sh);
    }
    if (H == 2) {
        // head0 chans l*4..+3 (row bytes l*8..+7), head1 at +64 (bytes 128+l*8)
        float4 b0 = *(const float4*)(b + l * 4);
        float4 b1 = *(const float4*)(b + 64 + l * 4);
        float r0[4], r1[4];
        float id0 = 1.f / fmaxf(den[0], 1e-16f);
        float id1 = 1.f / fmaxf(den[H - 1], 1e-16f);
        r0[0] = acc[0][0] * id0 + b0.x; r0[1] = acc[0][1] * id0 + b0.y;
        r0[2] = acc[0][2] * id0 + b0.z; r0[3] = acc[0][3] * id0 + b0.w;
        r1[0] = acc[H - 1][0] * id1 + b1.x; r1[1] = acc[H - 1][1] * id1 + b1.y;
        r1[2] = acc[H - 1][2] * id1 + b1.z; r1[3] = acc[H - 1][3] * id1 + b1.w;
        if (RELU) {
#pragma unroll
            for (int q = 0; q < 4; ++q) { r0[q] = fmaxf(r0[q], 0.f); r1[q] = fmaxf(r1[q], 0.f); }
        }
        uint2 p0 = make_uint2(pack_bf16x2(r0[0], r0[1]), pack_bf16x2(r0[2], r0[3]));
        uint2 p1 = make_uint2(pack_bf16x2(r1[0], r1[1]), pack_bf16x2(r1[2], r1[3]));
        if (FUSE2) {
            int g = threadIdx.x >> 4;        // local node 0..15 == LDS row
            int key = (g & 15) << 4;
            *(uint2*)(h1tile + g * 256 + ((l * 8) ^ key)) = p0;
            *(uint2*)(h1tile + g * 256 + ((128 + l * 8) ^ key)) = p1;
        } else {
            ushort_t* outb = (ushort_t*)outp;
            *(uint2*)(outb + (size_t)n * 128 + l * 4) = p0;
            *(uint2*)(outb + (size_t)n * 128 + 64 + l * 4) = p1;
        }
    } else {
        float4 bv = *(const float4*)(b + l * 4);
        float id0 = 1.f / fmaxf(den[0], 1e-16f);
        float4 r;
        r.x = acc[0][0] * id0 + bv.x; r.y = acc[0][1] * id0 + bv.y;
        r.z = acc[0][2] * id0 + bv.z; r.w = acc[0][3] * id0 + bv.w;
        if (RELU) { r.x = fmaxf(r.x, 0.f); r.y = fmaxf(r.y, 0.f);
                    r.z = fmaxf(r.z, 0.f); r.w = fmaxf(r.w, 0.f); }
        if (FPOOL) {
            // stage node's row in LDS [16][64] f32 (same values as old out2)
            float* pt = (float*)h1tile;
            int gl = threadIdx.x >> 4;       // local node 0..15
            *(float4*)(pt + gl * 64 + l * 4) = r;
        } else {
            *(float4*)((float*)outp + (size_t)n * 64 + l * 4) = r;
        }
    }

    if (FPOOL) {
        if (threadIdx.x < 16) batch_l[threadIdx.x] = batchp[blockIdx.x * 16 + threadIdx.x];
        __syncthreads();
        // pool_nodes' segment-local reduce over the LDS tile; boundaries
        // identical to the old 16-node pool chunks => bitwise-same partials.
        if (threadIdx.x < 64) {
            int c = threadIdx.x;
            const float* pt = (const float*)h1tile;
            int curg = batch_l[0];
            float s = 0.f, m = -1e30f;
            int cc = 0;
#pragma unroll
            for (int i = 0; i < 16; ++i) {
                int gg = batch_l[i];
                float v = pt[i * 64 + c];
                if (gg != curg) {
                    atomicAdd(&msum[curg * 64 + c], s);
                    atomicMax(&mmax[curg * 64 + c], enc_f32(m));
                    if (c == 0) atomicAdd(&cntb[curg], (float)cc);
                    s = 0.f; m = -1e30f; cc = 0; curg = gg;
                }
                s += v;
                m = fmaxf(m, v);
                ++cc;
            }
            atomicAdd(&msum[curg * 64 + c], s);
            atomicMax(&mmax[curg * 64 + c], enc_f32(m));
            if (c == 0) atomicAdd(&cntb[curg], (float)cc);
        }
    }

    if (FUSE2) {
        __syncthreads();
        // v11 gemm2 compute phase, A from LDS tile (same swizzle relation):
        // wave w owns cols w*16..w*16+15; 4 MFMAs over kc.
        int quad = lane >> 4, l16 = lane & 15;
        int skey = (l16 & 15) << 4;
        const char* swx = h1tile + l16 * 256;
        f32x4 acc2 = (f32x4){0.f, 0.f, 0.f, 0.f};
#pragma unroll
        for (int kc = 0; kc < 4; ++kc) {
            int bb_ = kc * 64 + quad * 16;   // byte of k = kc*32 + quad*8 (bf16)
            bf16x8 a = *(const bf16x8*)(swx + (bb_ ^ skey));
            bf16x8 bb = *(const bf16x8*)(Wp2 + (size_t)(wave * 16 + l16) * 128 + kc * 32 + quad * 8);
            acc2 = __builtin_amdgcn_mfma_f32_16x16x32_bf16(a, bb, acc2, 0, 0, 0);
        }
        float asv = as2v[wave * 16 + l16], adv2 = ad2v[wave * 16 + l16];
        size_t node0 = (size_t)blockIdx.x * 16;
#pragma unroll
        for (int r = 0; r < 4; ++r) {
            size_t row = node0 + quad * 4 + r;
            h2out[row * 64 + wave * 16 + l16] = f32_to_bf16(acc2[r]);
            float ps = acc2[r] * asv, pd = acc2[r] * adv2;
#pragma unroll
            for (int sh = 1; sh < 16; sh <<= 1) {
                ps += __shfl_xor(ps, sh);
                pd += __shfl_xor(pd, sh);
            }
            if (l16 == 0) {
                aspart[quad * 4 + r][wave] = ps;
                adpart[quad * 4 + r][wave] = pd;
            }
        }
        __syncthreads();
        int t = threadIdx.x;
        if (t < 16) {
            as2o[node0 + t] = aspart[t][0] + aspart[t][1] + aspart[t][2] + aspart[t][3];
        } else if (t < 32) {
            int rr = t - 16;
            ad2o[node0 + rr] = adpart[rr][0] + adpart[rr][1] + adpart[rr][2] + adpart[rr][3];
        }
    }
}

__global__ __launch_bounds__(64) void mlp_head(const float* __restrict__ msum,
                                               const unsigned* __restrict__ mmax,
                                               const float* __restrict__ cnt,
                                               const float* __restrict__ Wf1,
                                               const float* __restrict__ bf1,
                                               const float* __restrict__ Wf2,
                                               const float* __restrict__ bf2,
                                               float* __restrict__ out) {
    __shared__ float pooled[128];
    int g = blockIdx.x, lane = threadIdx.x;
    float c = cnt[g];
    pooled[lane] = msum[g * 64 + lane] / fmaxf(c, 1.0f);
    pooled[64 + lane] = (c > 0.f) ? dec_f32(mmax[g * 64 + lane]) : 0.f;
    __syncthreads();
    float acc = bf1[lane];
#pragma unroll
    for (int k = 0; k < 128; ++k) acc += pooled[k] * Wf1[k * 64 + lane];
    acc = fmaxf(acc, 0.f);
    float r = acc * Wf2[lane];
#pragma unroll
    for (int off = 32; off; off >>= 1) r += __shfl_xor(r, off);
    if (lane == 0) out[g] = r + bf2[0];
}

extern "C" void kernel_launch(void* const* d_in, const int* in_sizes, int n_in,
                              void* d_out, int out_size, void* d_ws, size_t ws_size,
                              hipStream_t stream) {
    const float* x    = (const float*)d_in[0];
    const int*   ei   = (const int*)d_in[1];
    const int*   batch= (const int*)d_in[2];
    const float* W1   = (const float*)d_in[3];
    const float* as1  = (const float*)d_in[4];
    const float* ad1  = (const float*)d_in[5];
    const float* b1   = (const float*)d_in[6];
    const float* W2   = (const float*)d_in[7];
    const float* as2  = (const float*)d_in[8];
    const float* ad2  = (const float*)d_in[9];
    const float* b2   = (const float*)d_in[10];
    const float* Wf1  = (const float*)d_in[11];
    const float* bf1  = (const float*)d_in[12];
    const float* Wf2  = (const float*)d_in[13];
    const float* bf2  = (const float*)d_in[14];
    float* out = (float*)d_out;

    const size_t N = N_NODESC;
    float* ws = (float*)d_ws;
    ushort_t* h16_1 = (ushort_t*)ws;               // N*128 bf16, head-interleaved
    ushort_t* xb16  = (ushort_t*)(ws + N * 64);    // N*128 bf16 X (was out1b)
    ushort_t* h16_2 = (ushort_t*)(ws + N * 128);   // N*64 bf16, natural
    float*    small = ws + N * 224;
    float*    as1b = small;                         // 2N
    float*    ad1b = small + 2 * N;                 // 2N
    float*    as2b = small + 4 * N;                 // N
    float*    ad2b = small + 5 * N;                 // N
    float*    msum = small + 6 * N;                 // 512*64
    unsigned* mmax = (unsigned*)(small + 6 * N + 512 * 64);
    float*    cntb = small + 6 * N + 2 * 512 * 64;  // 512
    int* ip  = (int*)(small + 6 * N + 2 * 512 * 64 + 512);
    int* deg  = ip;              // N
    int* off  = ip + N;          // N
    int* csr  = ip + 2 * N;      // E_TOT
    int* bsum = ip + 2 * N + E_TOTC;  // SCAN_NB
    ushort_t* wPre1 = (ushort_t*)(bsum + SCAN_NB);  // 128*128 bf16
    ushort_t* wPre2 = wPre1 + 128 * 128;            // 64*128 bf16

    const int NBLK16 = (N_NODESC + 15) / 16;   // 6250 (gemm1 1-wave; gathers)
    const int NBLKI  = (N_NODESC * 128 / 8 + 255) / 256;  // 6250 (init w/ X conv)

    // init + W pre-convert + X->bf16 (single dispatch, grid-strided guards)
    init_all<<<NBLKI, 256, 0, stream>>>(msum, mmax, cntb, deg, W1, W2,
                                        wPre1, wPre2, x, xb16);

    // ---- layer 1 GEMM (bf16 input) + fused hist ----
    gemm1_mfma<<<NBLK16, 64, 0, stream>>>(xb16, wPre1, as1, ad1, as1b, ad1b,
                                          h16_1, ei, deg, N);

    // CSR scan + scatter (hist already accumulated inside gemm1)
    scan_partial<<<SCAN_NB, 256, 0, stream>>>(deg, bsum, N);
    scan_final<<<SCAN_NB, 256, 0, stream>>>(deg, bsum, off, N);
    scatter_csr<<<(E_TOTC + 255) / 256, 256, 0, stream>>>(ei, off, csr);

    // ---- layer 1 aggregation (H=2) + fused layer-2 GEMM ----
    gat_gather<2, true, true, false><<<NBLK16, 256, 0, stream>>>(
        off, deg, csr, as1b, ad1b, h16_1, b1, nullptr,
        wPre2, as2, ad2, as2b, ad2b, h16_2,
        nullptr, nullptr, nullptr, nullptr, N);

    // ---- layer 2 aggregation (H=1) + fused pooling ----
    gat_gather<1, false, false, true><<<NBLK16, 256, 0, stream>>>(
        off, deg, csr, as2b, ad2b, h16_2, b2, nullptr,
        nullptr, nullptr, nullptr, nullptr, nullptr, nullptr,
        batch, msum, mmax, cntb, N);

    // ---- MLP head ----
    mlp_head<<<NUM_GRAPHSC, 64, 0, stream>>>(msum, mmax, cntb, Wf1, bf1, Wf2, bf2, out);
}

// Round 14
// 289.162 us; speedup vs baseline: 1.0041x; 1.0041x over previous
//
#include <hip/hip_runtime.h>

#define N_NODESC 100000
#define N_EDGESC 600000
#define E_TOTC   700000
#define NUM_GRAPHSC 512
#define NEG_SLOPE 0.2f
#define NEG_INF_ENC 0x007FFFFFu
#define SCAN_NB 128

typedef unsigned short ushort_t;
typedef __attribute__((ext_vector_type(8))) short bf16x8;   // 8 bf16 = 4 VGPR
typedef __attribute__((ext_vector_type(4))) float f32x4;    // MFMA accumulator

// monotone float<->uint mapping so unsigned atomicMax == float max
__device__ __forceinline__ unsigned enc_f32(float f) {
    unsigned u = __float_as_uint(f);
    return (u & 0x80000000u) ? ~u : (u | 0x80000000u);
}
__device__ __forceinline__ float dec_f32(unsigned u) {
    u = (u & 0x80000000u) ? (u ^ 0x80000000u) : ~u;
    return __uint_as_float(u);
}
// exact fp32->bf16 RNE (finite values) and bf16->fp32
__device__ __forceinline__ ushort_t f32_to_bf16(float f) {
    unsigned u = __float_as_uint(f);
    return (ushort_t)((u + 0x7FFFu + ((u >> 16) & 1u)) >> 16);
}
__device__ __forceinline__ float bf16_to_f32(ushort_t h) {
    return __uint_as_float(((unsigned)h) << 16);
}
__device__ __forceinline__ unsigned pack_bf16x2(float a, float b) {
    return (unsigned)f32_to_bf16(a) | ((unsigned)f32_to_bf16(b) << 16);
}

// register-free async global->LDS, width 16B (vmcnt-counted, no VGPR dest)
__device__ __forceinline__ void glds16(const void* g, void* l) {
    __builtin_amdgcn_global_load_lds(
        (const __attribute__((address_space(1))) void*)g,
        (__attribute__((address_space(3))) void*)l, 16, 0, 0);
}

// fused init: msum=0, mmax=-inf, cnt=0, deg=0, W1/W2 -> bf16 wPre, and
// X -> bf16 (grid-strided; same RNE gemm1 applied in-kernel before, so
// downstream numerics are BITWISE identical). Grid covers N*128/8 threads.
__global__ __launch_bounds__(256) void init_all(float* __restrict__ msum,
                                                unsigned* __restrict__ mmax,
                                                float* __restrict__ cnt,
                                                int* __restrict__ deg,
                                                const float* __restrict__ W1,
                                                const float* __restrict__ W2,
                                                ushort_t* __restrict__ wPre1,
                                                ushort_t* __restrict__ wPre2,
                                                const float* __restrict__ X,
                                                ushort_t* __restrict__ xb16) {
    int i = blockIdx.x * 256 + threadIdx.x;
    if (i < NUM_GRAPHSC * 64) { msum[i] = 0.f; mmax[i] = NEG_INF_ENC; }
    if (i < NUM_GRAPHSC) cnt[i] = 0.f;
    if (i < N_NODESC) deg[i] = 0;
    if (i < 128 * 128) {
        int n = i >> 7, k = i & 127;
        wPre1[n * 128 + k] = f32_to_bf16(W1[k * 128 + n]);
    } else if (i < 128 * 128 + 64 * 128) {
        int j = i - 128 * 128;
        int n = j >> 7, k = j & 127;
        wPre2[n * 128 + k] = f32_to_bf16(W2[k * 64 + n]);
    }
    if (i < N_NODESC * 128 / 8) {
        const float4* xp = (const float4*)(X + (size_t)i * 8);
        float4 a = xp[0], b = xp[1];
        uint4 o;
        o.x = pack_bf16x2(a.x, a.y);
        o.y = pack_bf16x2(a.z, a.w);
        o.z = pack_bf16x2(b.x, b.y);
        o.w = pack_bf16x2(b.z, b.w);
        *(uint4*)(xb16 + (size_t)i * 8) = o;
    }
}

// ---------------- CSR build ----------------
// R26: hist fused into gemm1 REGRESSED (gemm1 45->65us, WRITE +19MB from
// 700K scattered atomic sector write-throughs on the critical path -- same
// disease as R3's alpha atomics). Separate dispatch restored (v15-proven).
__global__ __launch_bounds__(256) void hist_dst(const int* __restrict__ ei,
                                                int* __restrict__ deg) {
    int e = blockIdx.x * blockDim.x + threadIdx.x;
    if (e >= E_TOTC) return;
    int d = (e < N_EDGESC) ? ei[N_EDGESC + e] : e - N_EDGESC;
    atomicAdd(&deg[d], 1);
}

__global__ __launch_bounds__(256) void scan_partial(const int* __restrict__ deg,
                                                    int* __restrict__ bsum, int n) {
    __shared__ int red[256];
    int chunk = (n + SCAN_NB - 1) / SCAN_NB;
    int lo = blockIdx.x * chunk, hi = min(lo + chunk, n);
    int s = 0;
    for (int i = lo + threadIdx.x; i < hi; i += 256) s += deg[i];
    red[threadIdx.x] = s;
    __syncthreads();
    for (int d = 128; d; d >>= 1) {
        if (threadIdx.x < d) red[threadIdx.x] += red[threadIdx.x + d];
        __syncthreads();
    }
    if (threadIdx.x == 0) bsum[blockIdx.x] = red[0];
}

__global__ __launch_bounds__(256) void scan_final(const int* __restrict__ deg,
                                                  const int* __restrict__ bsum,
                                                  int* __restrict__ off, int n) {
    __shared__ int bs[SCAN_NB];
    __shared__ int tile[256];
    __shared__ int carry;
    int t = threadIdx.x;
    if (t < SCAN_NB) bs[t] = bsum[t];
    __syncthreads();
    for (int d = 1; d < SCAN_NB; d <<= 1) {
        int v = (t >= d && t < SCAN_NB) ? bs[t - d] : 0;
        __syncthreads();
        if (t < SCAN_NB) bs[t] += v;
        __syncthreads();
    }
    if (t == 0) carry = blockIdx.x ? bs[blockIdx.x - 1] : 0;
    __syncthreads();
    int chunk = (n + SCAN_NB - 1) / SCAN_NB;
    int lo = blockIdx.x * chunk, hi = min(lo + chunk, n);
    for (int base = lo; base < hi; base += 256) {
        int i = base + t;
        int v = (i < hi) ? deg[i] : 0;
        tile[t] = v;
        __syncthreads();
        for (int d = 1; d < 256; d <<= 1) {
            int u = (t >= d) ? tile[t - d] : 0;
            __syncthreads();
            tile[t] += u;
            __syncthreads();
        }
        if (i < hi) off[i] = carry + tile[t] - v;
        __syncthreads();
        if (t == 0) carry += tile[255];
        __syncthreads();
    }
}

__global__ __launch_bounds__(256) void scatter_csr(const int* __restrict__ ei,
                                                   int* __restrict__ off,
                                                   int* __restrict__ csr) {
    int e = blockIdx.x * blockDim.x + threadIdx.x;
    if (e >= E_TOTC) return;
    int s, d;
    if (e < N_EDGESC) { s = ei[e]; d = ei[N_EDGESC + e]; } else { s = d = e - N_EDGESC; }
    int slot = atomicAdd(&off[d], 1);
    csr[slot] = s;
}

// ---------------- MFMA GEMM, layer 1 (v18: bf16 input, clean) ---------------
// v17's bf16 path isolated (hist fusion removed): 4 glds x 1KB (4 rows each),
// direct bf16x8 LDS reads, gemm2-proven swizzle relation. Half the staged
// bytes/requests of the fp32 version. Y-write + in-wave alpha verbatim v11.
// Fragment maps (m89/m91): A[m=lane&15][k=quad*8+j], B[n=lane&15][k=quad*8+j],
// D[row=quad*4+r][col=lane&15]. Y u32 col c = pack(head0 ch c, head1 ch c).
__global__ __launch_bounds__(64) void gemm1_mfma(const ushort_t* __restrict__ Xb,
                                                 const ushort_t* __restrict__ Wp,
                                                 const float* __restrict__ a_s,
                                                 const float* __restrict__ a_d,
                                                 float* __restrict__ as_out,
                                                 float* __restrict__ ad_out,
                                                 ushort_t* __restrict__ Y16, int N) {
    __shared__ ushort_t sx[2048];    // 4KB: 16 rows x 256B, source-swizzled
    int lane = threadIdx.x;
    int quad = lane >> 4, l16 = lane & 15;
    size_t node0 = (size_t)blockIdx.x * 16;

    // stage the tile: 4 chunks x 1KB (4 rows each) -- gemm2-proven geometry
    {
        int rq = lane >> 4;               // row within 4-row chunk
        int cb = (lane & 15) * 16;        // col byte 0..240
#pragma unroll
        for (int c = 0; c < 4; ++c) {
            int rl = 4 * c + rq;
            size_t grow = node0 + rl;
            if (grow >= (size_t)N) grow = N - 1;   // pad rows: consistent garbage
            int goff = cb ^ ((rl & 15) << 4);      // inverse swizzle on SOURCE
            glds16((const char*)(Xb + grow * 128) + goff,
                   (char*)sx + c * 1024);
        }
    }
    asm volatile("s_waitcnt vmcnt(0)" ::: "memory");
    __builtin_amdgcn_sched_barrier(0);

    const char* swx = (const char*)sx + l16 * 256;
    int skey = (l16 & 15) << 4;

    f32x4 acc[8];
#pragma unroll
    for (int ct = 0; ct < 8; ++ct) acc[ct] = (f32x4){0.f, 0.f, 0.f, 0.f};

#pragma unroll
    for (int kc = 0; kc < 4; ++kc) {
        int b = kc * 64 + quad * 16;      // byte of k = kc*32 + quad*8 (bf16)
        bf16x8 a = *(const bf16x8*)(swx + (b ^ skey));
#pragma unroll
        for (int ct = 0; ct < 8; ++ct) {
            bf16x8 bb = *(const bf16x8*)(Wp + (size_t)(ct * 16 + l16) * 128 + kc * 32 + quad * 8);
            acc[ct] = __builtin_amdgcn_mfma_f32_16x16x32_bf16(a, bb, acc[ct], 0, 0, 0);
        }
    }

    // Y write (clean full rows) + in-wave alpha (plain stores) [v11 verbatim]
    unsigned* Yu = (unsigned*)Y16;
    float asv0[4], asv1[4], adv0[4], adv1[4];
#pragma unroll
    for (int ct = 0; ct < 4; ++ct) {
        int c = ct * 16 + l16;
        asv0[ct] = a_s[c]; asv1[ct] = a_s[64 + c];
        adv0[ct] = a_d[c]; adv1[ct] = a_d[64 + c];
    }
#pragma unroll
    for (int r = 0; r < 4; ++r) {
        size_t row = node0 + quad * 4 + r;
        bool ok = row < (size_t)N;
        if (ok) {
#pragma unroll
            for (int ct = 0; ct < 4; ++ct)
                Yu[row * 64 + ct * 16 + l16] = pack_bf16x2(acc[ct][r], acc[ct + 4][r]);
        }
        float ps0 = 0.f, pd0 = 0.f, ps1 = 0.f, pd1 = 0.f;
#pragma unroll
        for (int ct = 0; ct < 4; ++ct) {
            ps0 += acc[ct][r] * asv0[ct];     pd0 += acc[ct][r] * adv0[ct];
            ps1 += acc[ct + 4][r] * asv1[ct]; pd1 += acc[ct + 4][r] * adv1[ct];
        }
#pragma unroll
        for (int sh = 1; sh < 16; sh <<= 1) {
            ps0 += __shfl_xor(ps0, sh); pd0 += __shfl_xor(pd0, sh);
            ps1 += __shfl_xor(ps1, sh); pd1 += __shfl_xor(pd1, sh);
        }
        if (l16 == 0 && ok) {
            *(float2*)(as_out + row * 2) = make_float2(ps0, ps1);
            *(float2*)(ad_out + row * 2) = make_float2(pd0, pd1);
        }
    }
}

// ---------------- fused gather aggregation (v16 body, unchanged) ------------
template <int H, bool RELU, bool FUSE2, bool FPOOL>
__global__ __launch_bounds__(256) void gat_gather(const int* __restrict__ off_end,
                                                  const int* __restrict__ deg,
                                                  const int* __restrict__ csr,
                                                  const float* __restrict__ as,
                                                  const float* __restrict__ ad,
                                                  const ushort_t* __restrict__ H16,
                                                  const float* __restrict__ b,
                                                  void* __restrict__ outp,
                                                  const ushort_t* __restrict__ Wp2,
                                                  const float* __restrict__ as2v,
                                                  const float* __restrict__ ad2v,
                                                  float* __restrict__ as2o,
                                                  float* __restrict__ ad2o,
                                                  ushort_t* __restrict__ h2out,
                                                  const int* __restrict__ batchp,
                                                  float* __restrict__ msum,
                                                  unsigned* __restrict__ mmax,
                                                  float* __restrict__ cntb,
                                                  int N) {
    __shared__ char h1tile[16 * 256];      // FUSE2: swizzled h1 rows / FPOOL: [16][64] f32
    __shared__ float aspart[16][4];
    __shared__ float adpart[16][4];
    __shared__ int batch_l[16];
    int lane = threadIdx.x & 63;
    int wave = threadIdx.x >> 6;
    int l = lane & 15;          // lane within group
    int gbase = lane & 48;      // group base lane in wave
    int n = blockIdx.x * 16 + wave * 4 + (lane >> 4);
    if (n >= N) return;         // never taken (N%16==0, exact grid)
    int dg = deg[n];
    int o = off_end[n] - dg;
    float adv[H];
#pragma unroll
    for (int h = 0; h < H; ++h) adv[h] = ad[n * H + h];

    float acc[H][4], den[H];
#pragma unroll
    for (int h = 0; h < H; ++h) {
        den[h] = 0.f;
#pragma unroll
        for (int q = 0; q < 4; ++q) acc[h][q] = 0.f;
    }

    const unsigned* Hu = (const unsigned*)H16;  // H==2: row = 64 u32 interleaved

    for (int base = 0; base < dg; base += 16) {
        int i = base + l;
        bool valid = i < dg;
        int s = valid ? csr[o + i] : 0;
        float v[H];
        if (H == 2) {
            float2 p = valid ? ((const float2*)as)[s] : make_float2(0.f, 0.f);
            v[0] = p.x + adv[0];
            v[H - 1] = p.y + adv[H - 1];
        } else {
            v[0] = valid ? as[s] + adv[0] : 0.f;
        }
#pragma unroll
        for (int h = 0; h < H; ++h) {
            float e = v[h] >= 0.f ? v[h] : NEG_SLOPE * v[h];
            v[h] = valid ? __expf(e) : 0.f;  // weight; 0 for invalid lanes
            den[h] += v[h];
        }
        int wpk = (H == 2) ? (int)pack_bf16x2(v[0], v[H - 1])
                           : (int)__float_as_uint(v[0]);
        int cnt = min(dg - base, 16);
        int cnt4 = (cnt + 3) & ~3;  // pad: lanes >= cnt have weight 0, s = 0
        for (int j = 0; j < cnt4; j += 4) {
#pragma unroll
            for (int u = 0; u < 4; ++u) {
                int src = gbase + j + u;     // per-lane index: serves all groups
                int sj = __shfl(s, src);
                int wp = __shfl(wpk, src);
                if (H == 2) {
                    float w0 = __uint_as_float(((unsigned)wp) << 16);
                    float w1 = __uint_as_float(((unsigned)wp) & 0xffff0000u);
                    uint4 hu = *(const uint4*)(Hu + (size_t)sj * 64 + l * 4);
                    acc[0][0] += w0 * __uint_as_float(hu.x << 16);
                    acc[H - 1][0] += w1 * __uint_as_float(hu.x & 0xffff0000u);
                    acc[0][1] += w0 * __uint_as_float(hu.y << 16);
                    acc[H - 1][1] += w1 * __uint_as_float(hu.y & 0xffff0000u);
                    acc[0][2] += w0 * __uint_as_float(hu.z << 16);
                    acc[H - 1][2] += w1 * __uint_as_float(hu.z & 0xffff0000u);
                    acc[0][3] += w0 * __uint_as_float(hu.w << 16);
                    acc[H - 1][3] += w1 * __uint_as_float(hu.w & 0xffff0000u);
                } else {
                    float w0 = __uint_as_float((unsigned)wp);
                    uint2 hu = *(const uint2*)((const unsigned*)(H16 + (size_t)sj * 64) + l * 2);
                    acc[0][0] += w0 * __uint_as_float(hu.x << 16);
                    acc[0][1] += w0 * __uint_as_float(hu.x & 0xffff0000u);
                    acc[0][2] += w0 * __uint_as_float(hu.y << 16);
                    acc[0][3] += w0 * __uint_as_float(hu.y & 0xffff0000u);
                }
            }
        }
    }
#pragma unroll
    for (int h = 0; h < H; ++h) {
#pragma unroll
        for (int sh = 8; sh; sh >>= 1) den[h] += __shfl_xor(den[h], sh);
    }
    if (H == 2) {
        // head0 chans l*4..+3 (row bytes l*8..+7), head1 at +64 (bytes 128+l*8)
        float4 b0 = *(const float4*)(b + l * 4);
        float4 b1 = *(const float4*)(b + 64 + l * 4);
        float r0[4], r1[4];
        float id0 = 1.f / fmaxf(den[0], 1e-16f);
        float id1 = 1.f / fmaxf(den[H - 1], 1e-16f);
        r0[0] = acc[0][0] * id0 + b0.x; r0[1] = acc[0][1] * id0 + b0.y;
        r0[2] = acc[0][2] * id0 + b0.z; r0[3] = acc[0][3] * id0 + b0.w;
        r1[0] = acc[H - 1][0] * id1 + b1.x; r1[1] = acc[H - 1][1] * id1 + b1.y;
        r1[2] = acc[H - 1][2] * id1 + b1.z; r1[3] = acc[H - 1][3] * id1 + b1.w;
        if (RELU) {
#pragma unroll
            for (int q = 0; q < 4; ++q) { r0[q] = fmaxf(r0[q], 0.f); r1[q] = fmaxf(r1[q], 0.f); }
        }
        uint2 p0 = make_uint2(pack_bf16x2(r0[0], r0[1]), pack_bf16x2(r0[2], r0[3]));
        uint2 p1 = make_uint2(pack_bf16x2(r1[0], r1[1]), pack_bf16x2(r1[2], r1[3]));
        if (FUSE2) {
            int g = threadIdx.x >> 4;        // local node 0..15 == LDS row
            int key = (g & 15) << 4;
            *(uint2*)(h1tile + g * 256 + ((l * 8) ^ key)) = p0;
            *(uint2*)(h1tile + g * 256 + ((128 + l * 8) ^ key)) = p1;
        } else {
            ushort_t* outb = (ushort_t*)outp;
            *(uint2*)(outb + (size_t)n * 128 + l * 4) = p0;
            *(uint2*)(outb + (size_t)n * 128 + 64 + l * 4) = p1;
        }
    } else {
        float4 bv = *(const float4*)(b + l * 4);
        float id0 = 1.f / fmaxf(den[0], 1e-16f);
        float4 r;
        r.x = acc[0][0] * id0 + bv.x; r.y = acc[0][1] * id0 + bv.y;
        r.z = acc[0][2] * id0 + bv.z; r.w = acc[0][3] * id0 + bv.w;
        if (RELU) { r.x = fmaxf(r.x, 0.f); r.y = fmaxf(r.y, 0.f);
                    r.z = fmaxf(r.z, 0.f); r.w = fmaxf(r.w, 0.f); }
        if (FPOOL) {
            // stage node's row in LDS [16][64] f32 (same values as old out2)
            float* pt = (float*)h1tile;
            int gl = threadIdx.x >> 4;       // local node 0..15
            *(float4*)(pt + gl * 64 + l * 4) = r;
        } else {
            *(float4*)((float*)outp + (size_t)n * 64 + l * 4) = r;
        }
    }

    if (FPOOL) {
        if (threadIdx.x < 16) batch_l[threadIdx.x] = batchp[blockIdx.x * 16 + threadIdx.x];
        __syncthreads();
        // pool_nodes' segment-local reduce over the LDS tile; boundaries
        // identical to the old 16-node pool chunks => bitwise-same partials.
        if (threadIdx.x < 64) {
            int c = threadIdx.x;
            const float* pt = (const float*)h1tile;
            int curg = batch_l[0];
            float s = 0.f, m = -1e30f;
            int cc = 0;
#pragma unroll
            for (int i = 0; i < 16; ++i) {
                int gg = batch_l[i];
                float v = pt[i * 64 + c];
                if (gg != curg) {
                    atomicAdd(&msum[curg * 64 + c], s);
                    atomicMax(&mmax[curg * 64 + c], enc_f32(m));
                    if (c == 0) atomicAdd(&cntb[curg], (float)cc);
                    s = 0.f; m = -1e30f; cc = 0; curg = gg;
                }
                s += v;
                m = fmaxf(m, v);
                ++cc;
            }
            atomicAdd(&msum[curg * 64 + c], s);
            atomicMax(&mmax[curg * 64 + c], enc_f32(m));
            if (c == 0) atomicAdd(&cntb[curg], (float)cc);
        }
    }

    if (FUSE2) {
        __syncthreads();
        // v11 gemm2 compute phase, A from LDS tile (same swizzle relation):
        // wave w owns cols w*16..w*16+15; 4 MFMAs over kc.
        int quad = lane >> 4, l16 = lane & 15;
        int skey = (l16 & 15) << 4;
        const char* swx = h1tile + l16 * 256;
        f32x4 acc2 = (f32x4){0.f, 0.f, 0.f, 0.f};
#pragma unroll
        for (int kc = 0; kc < 4; ++kc) {
            int bb_ = kc * 64 + quad * 16;   // byte of k = kc*32 + quad*8 (bf16)
            bf16x8 a = *(const bf16x8*)(swx + (bb_ ^ skey));
            bf16x8 bb = *(const bf16x8*)(Wp2 + (size_t)(wave * 16 + l16) * 128 + kc * 32 + quad * 8);
            acc2 = __builtin_amdgcn_mfma_f32_16x16x32_bf16(a, bb, acc2, 0, 0, 0);
        }
        float asv = as2v[wave * 16 + l16], adv2 = ad2v[wave * 16 + l16];
        size_t node0 = (size_t)blockIdx.x * 16;
#pragma unroll
        for (int r = 0; r < 4; ++r) {
            size_t row = node0 + quad * 4 + r;
            h2out[row * 64 + wave * 16 + l16] = f32_to_bf16(acc2[r]);
            float ps = acc2[r] * asv, pd = acc2[r] * adv2;
#pragma unroll
            for (int sh = 1; sh < 16; sh <<= 1) {
                ps += __shfl_xor(ps, sh);
                pd += __shfl_xor(pd, sh);
            }
            if (l16 == 0) {
                aspart[quad * 4 + r][wave] = ps;
                adpart[quad * 4 + r][wave] = pd;
            }
        }
        __syncthreads();
        int t = threadIdx.x;
        if (t < 16) {
            as2o[node0 + t] = aspart[t][0] + aspart[t][1] + aspart[t][2] + aspart[t][3];
        } else if (t < 32) {
            int rr = t - 16;
            ad2o[node0 + rr] = adpart[rr][0] + adpart[rr][1] + adpart[rr][2] + adpart[rr][3];
        }
    }
}

__global__ __launch_bounds__(64) void mlp_head(const float* __restrict__ msum,
                                               const unsigned* __restrict__ mmax,
                                               const float* __restrict__ cnt,
                                               const float* __restrict__ Wf1,
                                               const float* __restrict__ bf1,
                                               const float* __restrict__ Wf2,
                                               const float* __restrict__ bf2,
                                               float* __restrict__ out) {
    __shared__ float pooled[128];
    int g = blockIdx.x, lane = threadIdx.x;
    float c = cnt[g];
    pooled[lane] = msum[g * 64 + lane] / fmaxf(c, 1.0f);
    pooled[64 + lane] = (c > 0.f) ? dec_f32(mmax[g * 64 + lane]) : 0.f;
    __syncthreads();
    float acc = bf1[lane];
#pragma unroll
    for (int k = 0; k < 128; ++k) acc += pooled[k] * Wf1[k * 64 + lane];
    acc = fmaxf(acc, 0.f);
    float r = acc * Wf2[lane];
#pragma unroll
    for (int off = 32; off; off >>= 1) r += __shfl_xor(r, off);
    if (lane == 0) out[g] = r + bf2[0];
}

extern "C" void kernel_launch(void* const* d_in, const int* in_sizes, int n_in,
                              void* d_out, int out_size, void* d_ws, size_t ws_size,
                              hipStream_t stream) {
    const float* x    = (const float*)d_in[0];
    const int*   ei   = (const int*)d_in[1];
    const int*   batch= (const int*)d_in[2];
    const float* W1   = (const float*)d_in[3];
    const float* as1  = (const float*)d_in[4];
    const float* ad1  = (const float*)d_in[5];
    const float* b1   = (const float*)d_in[6];
    const float* W2   = (const float*)d_in[7];
    const float* as2  = (const float*)d_in[8];
    const float* ad2  = (const float*)d_in[9];
    const float* b2   = (const float*)d_in[10];
    const float* Wf1  = (const float*)d_in[11];
    const float* bf1  = (const float*)d_in[12];
    const float* Wf2  = (const float*)d_in[13];
    const float* bf2  = (const float*)d_in[14];
    float* out = (float*)d_out;

    const size_t N = N_NODESC;
    float* ws = (float*)d_ws;
    ushort_t* h16_1 = (ushort_t*)ws;               // N*128 bf16, head-interleaved
    ushort_t* xb16  = (ushort_t*)(ws + N * 64);    // N*128 bf16 X
    ushort_t* h16_2 = (ushort_t*)(ws + N * 128);   // N*64 bf16, natural
    float*    small = ws + N * 224;
    float*    as1b = small;                         // 2N
    float*    ad1b = small + 2 * N;                 // 2N
    float*    as2b = small + 4 * N;                 // N
    float*    ad2b = small + 5 * N;                 // N
    float*    msum = small + 6 * N;                 // 512*64
    unsigned* mmax = (unsigned*)(small + 6 * N + 512 * 64);
    float*    cntb = small + 6 * N + 2 * 512 * 64;  // 512
    int* ip  = (int*)(small + 6 * N + 2 * 512 * 64 + 512);
    int* deg  = ip;              // N
    int* off  = ip + N;          // N
    int* csr  = ip + 2 * N;      // E_TOT
    int* bsum = ip + 2 * N + E_TOTC;  // SCAN_NB
    ushort_t* wPre1 = (ushort_t*)(bsum + SCAN_NB);  // 128*128 bf16
    ushort_t* wPre2 = wPre1 + 128 * 128;            // 64*128 bf16

    const int NBLK16 = (N_NODESC + 15) / 16;   // 6250 (gemm1 1-wave; gathers)
    const int NBLKI  = (N_NODESC * 128 / 8 + 255) / 256;  // 6250 (init w/ X conv)

    // init + W pre-convert + X->bf16 (single dispatch, grid-strided guards)
    init_all<<<NBLKI, 256, 0, stream>>>(msum, mmax, cntb, deg, W1, W2,
                                        wPre1, wPre2, x, xb16);

    // CSR build (hist separate again -- R26 lesson)
    hist_dst<<<(E_TOTC + 255) / 256, 256, 0, stream>>>(ei, deg);
    scan_partial<<<SCAN_NB, 256, 0, stream>>>(deg, bsum, N);
    scan_final<<<SCAN_NB, 256, 0, stream>>>(deg, bsum, off, N);
    scatter_csr<<<(E_TOTC + 255) / 256, 256, 0, stream>>>(ei, off, csr);

    // ---- layer 1 GEMM (bf16 input) ----
    gemm1_mfma<<<NBLK16, 64, 0, stream>>>(xb16, wPre1, as1, ad1, as1b, ad1b,
                                          h16_1, N);

    // ---- layer 1 aggregation (H=2) + fused layer-2 GEMM ----
    gat_gather<2, true, true, false><<<NBLK16, 256, 0, stream>>>(
        off, deg, csr, as1b, ad1b, h16_1, b1, nullptr,
        wPre2, as2, ad2, as2b, ad2b, h16_2,
        nullptr, nullptr, nullptr, nullptr, N);

    // ---- layer 2 aggregation (H=1) + fused pooling ----
    gat_gather<1, false, false, true><<<NBLK16, 256, 0, stream>>>(
        off, deg, csr, as2b, ad2b, h16_2, b2, nullptr,
        nullptr, nullptr, nullptr, nullptr, nullptr, nullptr,
        batch, msum, mmax, cntb, N);

    // ---- MLP head ----
    mlp_head<<<NUM_GRAPHSC, 64, 0, stream>>>(msum, mmax, cntb, Wf1, bf1, Wf2, bf2, out);
}

// Round 15
// 283.102 us; speedup vs baseline: 1.0256x; 1.0214x over previous
//
#include <hip/hip_runtime.h>

#define N_NODESC 100000
#define N_EDGESC 600000
#define E_TOTC   700000
#define NUM_GRAPHSC 512
#define NEG_SLOPE 0.2f
#define NEG_INF_ENC 0x007FFFFFu
#define SCAN_NB 128

typedef unsigned short ushort_t;
typedef __attribute__((ext_vector_type(8))) short bf16x8;   // 8 bf16 = 4 VGPR
typedef __attribute__((ext_vector_type(4))) float f32x4;    // MFMA accumulator

// monotone float<->uint mapping so unsigned atomicMax == float max
__device__ __forceinline__ unsigned enc_f32(float f) {
    unsigned u = __float_as_uint(f);
    return (u & 0x80000000u) ? ~u : (u | 0x80000000u);
}
__device__ __forceinline__ float dec_f32(unsigned u) {
    u = (u & 0x80000000u) ? (u ^ 0x80000000u) : ~u;
    return __uint_as_float(u);
}
// exact fp32->bf16 RNE (finite values) and bf16->fp32
__device__ __forceinline__ ushort_t f32_to_bf16(float f) {
    unsigned u = __float_as_uint(f);
    return (ushort_t)((u + 0x7FFFu + ((u >> 16) & 1u)) >> 16);
}
__device__ __forceinline__ float bf16_to_f32(ushort_t h) {
    return __uint_as_float(((unsigned)h) << 16);
}
__device__ __forceinline__ unsigned pack_bf16x2(float a, float b) {
    return (unsigned)f32_to_bf16(a) | ((unsigned)f32_to_bf16(b) << 16);
}

// register-free async global->LDS, width 16B (vmcnt-counted, no VGPR dest)
__device__ __forceinline__ void glds16(const void* g, void* l) {
    __builtin_amdgcn_global_load_lds(
        (const __attribute__((address_space(1))) void*)g,
        (__attribute__((address_space(3))) void*)l, 16, 0, 0);
}

// fused init: msum=0, mmax=-inf, cnt=0, deg=0, and W1/W2 -> bf16 in MFMA
// B-fragment layout wPre[n][k].
// R27: v17/v18 proved X->bf16 pre-convert is cost-neutral at best (X must be
// read once at fp32 regardless; relocating the pack adds a 25.6MB write +
// dispatch). v16's fp32-in gemm1 restored -- measured best (285.9us).
__global__ __launch_bounds__(256) void init_all(float* __restrict__ msum,
                                                unsigned* __restrict__ mmax,
                                                float* __restrict__ cnt,
                                                int* __restrict__ deg,
                                                const float* __restrict__ W1,
                                                const float* __restrict__ W2,
                                                ushort_t* __restrict__ wPre1,
                                                ushort_t* __restrict__ wPre2) {
    int i = blockIdx.x * 256 + threadIdx.x;
    if (i < NUM_GRAPHSC * 64) { msum[i] = 0.f; mmax[i] = NEG_INF_ENC; }
    if (i < NUM_GRAPHSC) cnt[i] = 0.f;
    if (i < N_NODESC) deg[i] = 0;
    if (i < 128 * 128) {
        int n = i >> 7, k = i & 127;
        wPre1[n * 128 + k] = f32_to_bf16(W1[k * 128 + n]);
    } else if (i < 128 * 128 + 64 * 128) {
        int j = i - 128 * 128;
        int n = j >> 7, k = j & 127;
        wPre2[n * 128 + k] = f32_to_bf16(W2[k * 64 + n]);
    }
}

// ---------------- CSR build ----------------
__global__ __launch_bounds__(256) void hist_dst(const int* __restrict__ ei,
                                                int* __restrict__ deg) {
    int e = blockIdx.x * blockDim.x + threadIdx.x;
    if (e >= E_TOTC) return;
    int d = (e < N_EDGESC) ? ei[N_EDGESC + e] : e - N_EDGESC;
    atomicAdd(&deg[d], 1);
}

__global__ __launch_bounds__(256) void scan_partial(const int* __restrict__ deg,
                                                    int* __restrict__ bsum, int n) {
    __shared__ int red[256];
    int chunk = (n + SCAN_NB - 1) / SCAN_NB;
    int lo = blockIdx.x * chunk, hi = min(lo + chunk, n);
    int s = 0;
    for (int i = lo + threadIdx.x; i < hi; i += 256) s += deg[i];
    red[threadIdx.x] = s;
    __syncthreads();
    for (int d = 128; d; d >>= 1) {
        if (threadIdx.x < d) red[threadIdx.x] += red[threadIdx.x + d];
        __syncthreads();
    }
    if (threadIdx.x == 0) bsum[blockIdx.x] = red[0];
}

__global__ __launch_bounds__(256) void scan_final(const int* __restrict__ deg,
                                                  const int* __restrict__ bsum,
                                                  int* __restrict__ off, int n) {
    __shared__ int bs[SCAN_NB];
    __shared__ int tile[256];
    __shared__ int carry;
    int t = threadIdx.x;
    if (t < SCAN_NB) bs[t] = bsum[t];
    __syncthreads();
    for (int d = 1; d < SCAN_NB; d <<= 1) {
        int v = (t >= d && t < SCAN_NB) ? bs[t - d] : 0;
        __syncthreads();
        if (t < SCAN_NB) bs[t] += v;
        __syncthreads();
    }
    if (t == 0) carry = blockIdx.x ? bs[blockIdx.x - 1] : 0;
    __syncthreads();
    int chunk = (n + SCAN_NB - 1) / SCAN_NB;
    int lo = blockIdx.x * chunk, hi = min(lo + chunk, n);
    for (int base = lo; base < hi; base += 256) {
        int i = base + t;
        int v = (i < hi) ? deg[i] : 0;
        tile[t] = v;
        __syncthreads();
        for (int d = 1; d < 256; d <<= 1) {
            int u = (t >= d) ? tile[t - d] : 0;
            __syncthreads();
            tile[t] += u;
            __syncthreads();
        }
        if (i < hi) off[i] = carry + tile[t] - v;
        __syncthreads();
        if (t == 0) carry += tile[255];
        __syncthreads();
    }
}

__global__ __launch_bounds__(256) void scatter_csr(const int* __restrict__ ei,
                                                   int* __restrict__ off,
                                                   int* __restrict__ csr) {
    int e = blockIdx.x * blockDim.x + threadIdx.x;
    if (e >= E_TOTC) return;
    int s, d;
    if (e < N_EDGESC) { s = ei[e]; d = ei[N_EDGESC + e]; } else { s = d = e - N_EDGESC; }
    int slot = atomicAdd(&off[d], 1);
    csr[slot] = s;
}

// ---------------- MFMA GEMM, layer 1 (v11 config: structural floor) ---------
// R20: 8 structural variants all land 41-65us at ~1.2 TB/s -- one-shot
// 8KB-tile GEMM w/ epilogue is service-rate-limited on this part. Frozen.
// Fragment maps (m89/m91): A[m=lane&15][k=quad*8+j], B[n=lane&15][k=quad*8+j],
// D[row=quad*4+r][col=lane&15]. Y u32 col c = pack(head0 ch c, head1 ch c).
__global__ __launch_bounds__(64) void gemm1_mfma(const float* __restrict__ X,
                                                 const ushort_t* __restrict__ Wp,
                                                 const float* __restrict__ a_s,
                                                 const float* __restrict__ a_d,
                                                 float* __restrict__ as_out,
                                                 float* __restrict__ ad_out,
                                                 ushort_t* __restrict__ Y16, int N) {
    __shared__ float sx[2048];       // 8KB: 16 rows x 512B, source-swizzled
    int lane = threadIdx.x;
    int quad = lane >> 4, l16 = lane & 15;
    size_t node0 = (size_t)blockIdx.x * 16;

    // stage the tile: 8 chunks x 1KB (2 rows each)
    {
        int rhalf = lane >> 5;            // row parity within chunk
        int cb = (lane & 31) * 16;        // col byte 0..496
#pragma unroll
        for (int c = 0; c < 8; ++c) {
            int rl = 2 * c + rhalf;       // tile-local row 0..15
            size_t grow = node0 + rl;
            if (grow >= (size_t)N) grow = N - 1;   // pad rows: consistent garbage
            int goff = cb ^ ((rl & 15) << 4);      // inverse swizzle on SOURCE
            glds16((const char*)(X + grow * 128) + goff,
                   (char*)sx + c * 1024);
        }
    }
    asm volatile("s_waitcnt vmcnt(0)" ::: "memory");
    __builtin_amdgcn_sched_barrier(0);

    const char* swx = (const char*)sx + l16 * 512;
    int skey = (l16 & 15) << 4;

    f32x4 acc[8];
#pragma unroll
    for (int ct = 0; ct < 8; ++ct) acc[ct] = (f32x4){0.f, 0.f, 0.f, 0.f};

#pragma unroll
    for (int kc = 0; kc < 4; ++kc) {
        int b = kc * 128 + quad * 32;     // byte of k = kc*32 + quad*8
        float4 xa = *(const float4*)(swx + (b ^ skey));
        float4 xb = *(const float4*)(swx + ((b + 16) ^ skey));
        union { bf16x8 v; unsigned u[4]; } af;
        af.u[0] = pack_bf16x2(xa.x, xa.y);
        af.u[1] = pack_bf16x2(xa.z, xa.w);
        af.u[2] = pack_bf16x2(xb.x, xb.y);
        af.u[3] = pack_bf16x2(xb.z, xb.w);
#pragma unroll
        for (int ct = 0; ct < 8; ++ct) {
            bf16x8 bb = *(const bf16x8*)(Wp + (size_t)(ct * 16 + l16) * 128 + kc * 32 + quad * 8);
            acc[ct] = __builtin_amdgcn_mfma_f32_16x16x32_bf16(af.v, bb, acc[ct], 0, 0, 0);
        }
    }

    // Y write (clean full rows) + in-wave alpha (plain stores)
    unsigned* Yu = (unsigned*)Y16;
    float asv0[4], asv1[4], adv0[4], adv1[4];
#pragma unroll
    for (int ct = 0; ct < 4; ++ct) {
        int c = ct * 16 + l16;
        asv0[ct] = a_s[c]; asv1[ct] = a_s[64 + c];
        adv0[ct] = a_d[c]; adv1[ct] = a_d[64 + c];
    }
#pragma unroll
    for (int r = 0; r < 4; ++r) {
        size_t row = node0 + quad * 4 + r;
        bool ok = row < (size_t)N;
        if (ok) {
#pragma unroll
            for (int ct = 0; ct < 4; ++ct)
                Yu[row * 64 + ct * 16 + l16] = pack_bf16x2(acc[ct][r], acc[ct + 4][r]);
        }
        float ps0 = 0.f, pd0 = 0.f, ps1 = 0.f, pd1 = 0.f;
#pragma unroll
        for (int ct = 0; ct < 4; ++ct) {
            ps0 += acc[ct][r] * asv0[ct];     pd0 += acc[ct][r] * adv0[ct];
            ps1 += acc[ct + 4][r] * asv1[ct]; pd1 += acc[ct + 4][r] * adv1[ct];
        }
#pragma unroll
        for (int sh = 1; sh < 16; sh <<= 1) {
            ps0 += __shfl_xor(ps0, sh); pd0 += __shfl_xor(pd0, sh);
            ps1 += __shfl_xor(ps1, sh); pd1 += __shfl_xor(pd1, sh);
        }
        if (l16 == 0 && ok) {
            *(float2*)(as_out + row * 2) = make_float2(ps0, ps1);
            *(float2*)(ad_out + row * 2) = make_float2(pd0, pd1);
        }
    }
}

// ---------------- fused gather aggregation (v16 body: FUSE2 + FPOOL) --------
template <int H, bool RELU, bool FUSE2, bool FPOOL>
__global__ __launch_bounds__(256) void gat_gather(const int* __restrict__ off_end,
                                                  const int* __restrict__ deg,
                                                  const int* __restrict__ csr,
                                                  const float* __restrict__ as,
                                                  const float* __restrict__ ad,
                                                  const ushort_t* __restrict__ H16,
                                                  const float* __restrict__ b,
                                                  void* __restrict__ outp,
                                                  const ushort_t* __restrict__ Wp2,
                                                  const float* __restrict__ as2v,
                                                  const float* __restrict__ ad2v,
                                                  float* __restrict__ as2o,
                                                  float* __restrict__ ad2o,
                                                  ushort_t* __restrict__ h2out,
                                                  const int* __restrict__ batchp,
                                                  float* __restrict__ msum,
                                                  unsigned* __restrict__ mmax,
                                                  float* __restrict__ cntb,
                                                  int N) {
    __shared__ char h1tile[16 * 256];      // FUSE2: swizzled h1 rows / FPOOL: [16][64] f32
    __shared__ float aspart[16][4];
    __shared__ float adpart[16][4];
    __shared__ int batch_l[16];
    int lane = threadIdx.x & 63;
    int wave = threadIdx.x >> 6;
    int l = lane & 15;          // lane within group
    int gbase = lane & 48;      // group base lane in wave
    int n = blockIdx.x * 16 + wave * 4 + (lane >> 4);
    if (n >= N) return;         // never taken (N%16==0, exact grid)
    int dg = deg[n];
    int o = off_end[n] - dg;
    float adv[H];
#pragma unroll
    for (int h = 0; h < H; ++h) adv[h] = ad[n * H + h];

    float acc[H][4], den[H];
#pragma unroll
    for (int h = 0; h < H; ++h) {
        den[h] = 0.f;
#pragma unroll
        for (int q = 0; q < 4; ++q) acc[h][q] = 0.f;
    }

    const unsigned* Hu = (const unsigned*)H16;  // H==2: row = 64 u32 interleaved

    for (int base = 0; base < dg; base += 16) {
        int i = base + l;
        bool valid = i < dg;
        int s = valid ? csr[o + i] : 0;
        float v[H];
        if (H == 2) {
            float2 p = valid ? ((const float2*)as)[s] : make_float2(0.f, 0.f);
            v[0] = p.x + adv[0];
            v[H - 1] = p.y + adv[H - 1];
        } else {
            v[0] = valid ? as[s] + adv[0] : 0.f;
        }
#pragma unroll
        for (int h = 0; h < H; ++h) {
            float e = v[h] >= 0.f ? v[h] : NEG_SLOPE * v[h];
            v[h] = valid ? __expf(e) : 0.f;  // weight; 0 for invalid lanes
            den[h] += v[h];
        }
        int wpk = (H == 2) ? (int)pack_bf16x2(v[0], v[H - 1])
                           : (int)__float_as_uint(v[0]);
        int cnt = min(dg - base, 16);
        int cnt4 = (cnt + 3) & ~3;  // pad: lanes >= cnt have weight 0, s = 0
        for (int j = 0; j < cnt4; j += 4) {
#pragma unroll
            for (int u = 0; u < 4; ++u) {
                int src = gbase + j + u;     // per-lane index: serves all groups
                int sj = __shfl(s, src);
                int wp = __shfl(wpk, src);
                if (H == 2) {
                    float w0 = __uint_as_float(((unsigned)wp) << 16);
                    float w1 = __uint_as_float(((unsigned)wp) & 0xffff0000u);
                    uint4 hu = *(const uint4*)(Hu + (size_t)sj * 64 + l * 4);
                    acc[0][0] += w0 * __uint_as_float(hu.x << 16);
                    acc[H - 1][0] += w1 * __uint_as_float(hu.x & 0xffff0000u);
                    acc[0][1] += w0 * __uint_as_float(hu.y << 16);
                    acc[H - 1][1] += w1 * __uint_as_float(hu.y & 0xffff0000u);
                    acc[0][2] += w0 * __uint_as_float(hu.z << 16);
                    acc[H - 1][2] += w1 * __uint_as_float(hu.z & 0xffff0000u);
                    acc[0][3] += w0 * __uint_as_float(hu.w << 16);
                    acc[H - 1][3] += w1 * __uint_as_float(hu.w & 0xffff0000u);
                } else {
                    float w0 = __uint_as_float((unsigned)wp);
                    uint2 hu = *(const uint2*)((const unsigned*)(H16 + (size_t)sj * 64) + l * 2);
                    acc[0][0] += w0 * __uint_as_float(hu.x << 16);
                    acc[0][1] += w0 * __uint_as_float(hu.x & 0xffff0000u);
                    acc[0][2] += w0 * __uint_as_float(hu.y << 16);
                    acc[0][3] += w0 * __uint_as_float(hu.y & 0xffff0000u);
                }
            }
        }
    }
#pragma unroll
    for (int h = 0; h < H; ++h) {
#pragma unroll
        for (int sh = 8; sh; sh >>= 1) den[h] += __shfl_xor(den[h], sh);
    }
    if (H == 2) {
        // head0 chans l*4..+3 (row bytes l*8..+7), head1 at +64 (bytes 128+l*8)
        float4 b0 = *(const float4*)(b + l * 4);
        float4 b1 = *(const float4*)(b + 64 + l * 4);
        float r0[4], r1[4];
        float id0 = 1.f / fmaxf(den[0], 1e-16f);
        float id1 = 1.f / fmaxf(den[H - 1], 1e-16f);
        r0[0] = acc[0][0] * id0 + b0.x; r0[1] = acc[0][1] * id0 + b0.y;
        r0[2] = acc[0][2] * id0 + b0.z; r0[3] = acc[0][3] * id0 + b0.w;
        r1[0] = acc[H - 1][0] * id1 + b1.x; r1[1] = acc[H - 1][1] * id1 + b1.y;
        r1[2] = acc[H - 1][2] * id1 + b1.z; r1[3] = acc[H - 1][3] * id1 + b1.w;
        if (RELU) {
#pragma unroll
            for (int q = 0; q < 4; ++q) { r0[q] = fmaxf(r0[q], 0.f); r1[q] = fmaxf(r1[q], 0.f); }
        }
        uint2 p0 = make_uint2(pack_bf16x2(r0[0], r0[1]), pack_bf16x2(r0[2], r0[3]));
        uint2 p1 = make_uint2(pack_bf16x2(r1[0], r1[1]), pack_bf16x2(r1[2], r1[3]));
        if (FUSE2) {
            int g = threadIdx.x >> 4;        // local node 0..15 == LDS row
            int key = (g & 15) << 4;
            *(uint2*)(h1tile + g * 256 + ((l * 8) ^ key)) = p0;
            *(uint2*)(h1tile + g * 256 + ((128 + l * 8) ^ key)) = p1;
        } else {
            ushort_t* outb = (ushort_t*)outp;
            *(uint2*)(outb + (size_t)n * 128 + l * 4) = p0;
            *(uint2*)(outb + (size_t)n * 128 + 64 + l * 4) = p1;
        }
    } else {
        float4 bv = *(const float4*)(b + l * 4);
        float id0 = 1.f / fmaxf(den[0], 1e-16f);
        float4 r;
        r.x = acc[0][0] * id0 + bv.x; r.y = acc[0][1] * id0 + bv.y;
        r.z = acc[0][2] * id0 + bv.z; r.w = acc[0][3] * id0 + bv.w;
        if (RELU) { r.x = fmaxf(r.x, 0.f); r.y = fmaxf(r.y, 0.f);
                    r.z = fmaxf(r.z, 0.f); r.w = fmaxf(r.w, 0.f); }
        if (FPOOL) {
            // stage node's row in LDS [16][64] f32 (same values as old out2)
            float* pt = (float*)h1tile;
            int gl = threadIdx.x >> 4;       // local node 0..15
            *(float4*)(pt + gl * 64 + l * 4) = r;
        } else {
            *(float4*)((float*)outp + (size_t)n * 64 + l * 4) = r;
        }
    }

    if (FPOOL) {
        if (threadIdx.x < 16) batch_l[threadIdx.x] = batchp[blockIdx.x * 16 + threadIdx.x];
        __syncthreads();
        // pool_nodes' segment-local reduce over the LDS tile; boundaries
        // identical to the old 16-node pool chunks => bitwise-same partials.
        if (threadIdx.x < 64) {
            int c = threadIdx.x;
            const float* pt = (const float*)h1tile;
            int curg = batch_l[0];
            float s = 0.f, m = -1e30f;
            int cc = 0;
#pragma unroll
            for (int i = 0; i < 16; ++i) {
                int gg = batch_l[i];
                float v = pt[i * 64 + c];
                if (gg != curg) {
                    atomicAdd(&msum[curg * 64 + c], s);
                    atomicMax(&mmax[curg * 64 + c], enc_f32(m));
                    if (c == 0) atomicAdd(&cntb[curg], (float)cc);
                    s = 0.f; m = -1e30f; cc = 0; curg = gg;
                }
                s += v;
                m = fmaxf(m, v);
                ++cc;
            }
            atomicAdd(&msum[curg * 64 + c], s);
            atomicMax(&mmax[curg * 64 + c], enc_f32(m));
            if (c == 0) atomicAdd(&cntb[curg], (float)cc);
        }
    }

    if (FUSE2) {
        __syncthreads();
        // v11 gemm2 compute phase, A from LDS tile (same swizzle relation):
        // wave w owns cols w*16..w*16+15; 4 MFMAs over kc.
        int quad = lane >> 4, l16 = lane & 15;
        int skey = (l16 & 15) << 4;
        const char* swx = h1tile + l16 * 256;
        f32x4 acc2 = (f32x4){0.f, 0.f, 0.f, 0.f};
#pragma unroll
        for (int kc = 0; kc < 4; ++kc) {
            int bb_ = kc * 64 + quad * 16;   // byte of k = kc*32 + quad*8 (bf16)
            bf16x8 a = *(const bf16x8*)(swx + (bb_ ^ skey));
            bf16x8 bb = *(const bf16x8*)(Wp2 + (size_t)(wave * 16 + l16) * 128 + kc * 32 + quad * 8);
            acc2 = __builtin_amdgcn_mfma_f32_16x16x32_bf16(a, bb, acc2, 0, 0, 0);
        }
        float asv = as2v[wave * 16 + l16], adv2 = ad2v[wave * 16 + l16];
        size_t node0 = (size_t)blockIdx.x * 16;
#pragma unroll
        for (int r = 0; r < 4; ++r) {
            size_t row = node0 + quad * 4 + r;
            h2out[row * 64 + wave * 16 + l16] = f32_to_bf16(acc2[r]);
            float ps = acc2[r] * asv, pd = acc2[r] * adv2;
#pragma unroll
            for (int sh = 1; sh < 16; sh <<= 1) {
                ps += __shfl_xor(ps, sh);
                pd += __shfl_xor(pd, sh);
            }
            if (l16 == 0) {
                aspart[quad * 4 + r][wave] = ps;
                adpart[quad * 4 + r][wave] = pd;
            }
        }
        __syncthreads();
        int t = threadIdx.x;
        if (t < 16) {
            as2o[node0 + t] = aspart[t][0] + aspart[t][1] + aspart[t][2] + aspart[t][3];
        } else if (t < 32) {
            int rr = t - 16;
            ad2o[node0 + rr] = adpart[rr][0] + adpart[rr][1] + adpart[rr][2] + adpart[rr][3];
        }
    }
}

__global__ __launch_bounds__(64) void mlp_head(const float* __restrict__ msum,
                                               const unsigned* __restrict__ mmax,
                                               const float* __restrict__ cnt,
                                               const float* __restrict__ Wf1,
                                               const float* __restrict__ bf1,
                                               const float* __restrict__ Wf2,
                                               const float* __restrict__ bf2,
                                               float* __restrict__ out) {
    __shared__ float pooled[128];
    int g = blockIdx.x, lane = threadIdx.x;
    float c = cnt[g];
    pooled[lane] = msum[g * 64 + lane] / fmaxf(c, 1.0f);
    pooled[64 + lane] = (c > 0.f) ? dec_f32(mmax[g * 64 + lane]) : 0.f;
    __syncthreads();
    float acc = bf1[lane];
#pragma unroll
    for (int k = 0; k < 128; ++k) acc += pooled[k] * Wf1[k * 64 + lane];
    acc = fmaxf(acc, 0.f);
    float r = acc * Wf2[lane];
#pragma unroll
    for (int off = 32; off; off >>= 1) r += __shfl_xor(r, off);
    if (lane == 0) out[g] = r + bf2[0];
}

extern "C" void kernel_launch(void* const* d_in, const int* in_sizes, int n_in,
                              void* d_out, int out_size, void* d_ws, size_t ws_size,
                              hipStream_t stream) {
    const float* x    = (const float*)d_in[0];
    const int*   ei   = (const int*)d_in[1];
    const int*   batch= (const int*)d_in[2];
    const float* W1   = (const float*)d_in[3];
    const float* as1  = (const float*)d_in[4];
    const float* ad1  = (const float*)d_in[5];
    const float* b1   = (const float*)d_in[6];
    const float* W2   = (const float*)d_in[7];
    const float* as2  = (const float*)d_in[8];
    const float* ad2  = (const float*)d_in[9];
    const float* b2   = (const float*)d_in[10];
    const float* Wf1  = (const float*)d_in[11];
    const float* bf1  = (const float*)d_in[12];
    const float* Wf2  = (const float*)d_in[13];
    const float* bf2  = (const float*)d_in[14];
    float* out = (float*)d_out;

    const size_t N = N_NODESC;
    float* ws = (float*)d_ws;
    ushort_t* h16_1 = (ushort_t*)ws;               // N*128 bf16, head-interleaved
    ushort_t* h16_2 = (ushort_t*)(ws + N * 128);   // N*64 bf16, natural
    float*    small = ws + N * 224;
    float*    as1b = small;                         // 2N
    float*    ad1b = small + 2 * N;                 // 2N
    float*    as2b = small + 4 * N;                 // N
    float*    ad2b = small + 5 * N;                 // N
    float*    msum = small + 6 * N;                 // 512*64
    unsigned* mmax = (unsigned*)(small + 6 * N + 512 * 64);
    float*    cntb = small + 6 * N + 2 * 512 * 64;  // 512
    int* ip  = (int*)(small + 6 * N + 2 * 512 * 64 + 512);
    int* deg  = ip;              // N
    int* off  = ip + N;          // N
    int* csr  = ip + 2 * N;      // E_TOT
    int* bsum = ip + 2 * N + E_TOTC;  // SCAN_NB
    ushort_t* wPre1 = (ushort_t*)(bsum + SCAN_NB);  // 128*128 bf16
    ushort_t* wPre2 = wPre1 + 128 * 128;            // 64*128 bf16

    // init + W pre-convert (single dispatch)
    init_all<<<(N_NODESC + 255) / 256, 256, 0, stream>>>(msum, mmax, cntb, deg,
                                                         W1, W2, wPre1, wPre2);

    // CSR build (reused by both layers); hist includes self-loops
    hist_dst<<<(E_TOTC + 255) / 256, 256, 0, stream>>>(ei, deg);
    scan_partial<<<SCAN_NB, 256, 0, stream>>>(deg, bsum, N);
    scan_final<<<SCAN_NB, 256, 0, stream>>>(deg, bsum, off, N);
    scatter_csr<<<(E_TOTC + 255) / 256, 256, 0, stream>>>(ei, off, csr);

    const int NBLK16 = (N_NODESC + 15) / 16;   // 6250 (gemm1 1-wave; gathers)

    // ---- layer 1 GEMM (fp32 input, converts in-kernel; v16-proven) ----
    gemm1_mfma<<<NBLK16, 64, 0, stream>>>(x, wPre1, as1, ad1, as1b, ad1b, h16_1, N);

    // ---- layer 1 aggregation (H=2) + fused layer-2 GEMM ----
    gat_gather<2, true, true, false><<<NBLK16, 256, 0, stream>>>(
        off, deg, csr, as1b, ad1b, h16_1, b1, nullptr,
        wPre2, as2, ad2, as2b, ad2b, h16_2,
        nullptr, nullptr, nullptr, nullptr, N);

    // ---- layer 2 aggregation (H=1) + fused pooling ----
    gat_gather<1, false, false, true><<<NBLK16, 256, 0, stream>>>(
        off, deg, csr, as2b, ad2b, h16_2, b2, nullptr,
        nullptr, nullptr, nullptr, nullptr, nullptr, nullptr,
        batch, msum, mmax, cntb, N);

    // ---- MLP head ----
    mlp_head<<<NUM_GRAPHSC, 64, 0, stream>>>(msum, mmax, cntb, Wf1, bf1, Wf2, bf2, out);
}